// Round 15
// baseline (217.124 us; speedup 1.0000x reference)
//
#include <hip/hip_runtime.h>

// out[e,i] = sum_j mat[e,i,j] v[e,j] + bias[e,i],  [mat|bias] = MLP(pos).reshape(32,33)
// Round-16: r14 (8 waves x 32 edges, 4 waves/SIMD) with arch demand trimmed to the
// cap-64 budget. Occupancy model (r7-r14): arg2=k -> arch cap 256/k, k waves/SIMD.
// r14 hit 4 waves/SIMD (occ 40%) but spilled (demand ~80 > 64). Trims:
//   - oa ih-split: oa[2][4]=8 (was 16); store+reinit at the IH0/IH1 straddle
//   - W1/b1 slice in LDS (volatile per-half reads, not resident regs): -20
//   - pair-wise bfr loads (2+2) with p0/p1 live: transient peak -8
//   P[e, col] = h2[e,0:128] @ Wpack[0:128, col]   (col = j*32+i; W3-only)
//   out[e,i]  = sum_{col: i} vext[e,j] * P[e,col] + (b3 mini-GEMM C-init)
// LDS 53760 B: h1c[64][136]@0 / h2n[64][136]@17408 (prologue), vt[33][260]@0
// (G, overlays), Bb u16[2][4096]@34816, w1L[512]f32@51200, b1L[128]f32@53248.
// ws: Wg2 @0 (270336), W2f @270336 (32768), b3f @303104 (2048), b3c @305152 (128).

#define E_TOTAL 262144
#define EPB 256
#define NBLK (E_TOTAL / EPB)

typedef float f32x4 __attribute__((ext_vector_type(4)));
typedef short s8v  __attribute__((ext_vector_type(8)));
typedef short s4v  __attribute__((ext_vector_type(4)));
typedef unsigned int u32;

__device__ __forceinline__ unsigned short f2bf(float x) {
  unsigned u = __float_as_uint(x);
  u += 0x7fffu + ((u >> 16) & 1u);
  return (unsigned short)(u >> 16);
}

__device__ __forceinline__ void ld16_g2l(const void* g, void* l) {
  __builtin_amdgcn_global_load_lds((const __attribute__((address_space(1))) u32*)g,
                                   (__attribute__((address_space(3))) u32*)l, 16, 0, 0);
}

// ---------------- prep: pack W2/W3/b3 into MFMA B-fragment order ----------------
__global__ void prep_pack(const float* __restrict__ W2, const float* __restrict__ W3,
                          const float* __restrict__ b3,
                          unsigned short* __restrict__ Wg2, unsigned short* __restrict__ W2f,
                          unsigned short* __restrict__ b3f, float* __restrict__ b3c) {
  int idx = blockIdx.x * 256 + threadIdx.x;   // 528 blocks cover 135168
  if (idx < 135168) {
    int k = idx / 1056, c = idx % 1056;
    int i = c / 33, jc = c % 33;
    int col = jc * 32 + i;                    // Wg2 col = j*32 + i
    int nnt = col >> 4, low = col & 15;
    int nn = (nnt & 1) ? (33 + (nnt >> 1)) : (nnt >> 1);   // permuted tile order
    int ks = k >> 5, kr = k & 31;
    int lane = ((kr >> 3) << 4) + low;
    int jj = k & 7;
    Wg2[((nn * 4 + ks) * 64 + lane) * 8 + jj] = f2bf(W3[idx]);
  }
  if (idx < 16384) {
    int k = idx >> 7, n = idx & 127;
    int ks = k >> 5, kr = k & 31;
    int nt = n >> 4, low = n & 15;
    int l = ((kr >> 3) << 4) + low;
    int jj = k & 7;
    W2f[((ks * 8 + nt) * 64 + l) * 8 + jj] = f2bf(W2[idx]);
  }
  if (idx < 1024) {
    int jj = idx & 7, lane = (idx >> 3) & 63, ih = idx >> 9;
    int j = ((lane >> 4) << 3) + jj, i = ih * 16 + (lane & 15);
    b3f[idx] = f2bf(b3[i * 33 + j]);
  }
  if (idx < 32) b3c[idx] = b3[idx * 33 + 32];
}

// ---------------- G-loop tile compute (per-wave 32 edges; oa is CURRENT ih half) ----
__device__ __forceinline__ void tile_compute(const unsigned short* __restrict__ buf, int t,
                                             const float* __restrict__ vp0, int j,
                                             int lane,
                                             const s8v (&af)[2][4], float (&oa)[2][4]) {
  const f32x4 zero4 = {0.f, 0.f, 0.f, 0.f};
  f32x4 p0, p1;
  {
    s8v bA = *(const s8v*)&buf[(t * 4 + 0) * 512 + lane * 8];
    s8v bB = *(const s8v*)&buf[(t * 4 + 1) * 512 + lane * 8];
    p0 = __builtin_amdgcn_mfma_f32_16x16x32_bf16(af[0][0], bA, zero4, 0, 0, 0);
    p1 = __builtin_amdgcn_mfma_f32_16x16x32_bf16(af[1][0], bA, zero4, 0, 0, 0);
    p0 = __builtin_amdgcn_mfma_f32_16x16x32_bf16(af[0][1], bB, p0, 0, 0, 0);
    p1 = __builtin_amdgcn_mfma_f32_16x16x32_bf16(af[1][1], bB, p1, 0, 0, 0);
  }
  {
    s8v bA = *(const s8v*)&buf[(t * 4 + 2) * 512 + lane * 8];
    s8v bB = *(const s8v*)&buf[(t * 4 + 3) * 512 + lane * 8];
    p0 = __builtin_amdgcn_mfma_f32_16x16x32_bf16(af[0][2], bA, p0, 0, 0, 0);
    p1 = __builtin_amdgcn_mfma_f32_16x16x32_bf16(af[1][2], bA, p1, 0, 0, 0);
    p0 = __builtin_amdgcn_mfma_f32_16x16x32_bf16(af[0][3], bB, p0, 0, 0, 0);
    p1 = __builtin_amdgcn_mfma_f32_16x16x32_bf16(af[1][3], bB, p1, 0, 0, 0);
  }
  const float* vp = vp0 + j * 260;
  f32x4 vv0 = *(const f32x4*)(vp);
  f32x4 vv1 = *(const f32x4*)(vp + 16);
#pragma unroll
  for (int r = 0; r < 4; ++r) oa[0][r] += vv0[r] * p0[r];
#pragma unroll
  for (int r = 0; r < 4; ++r) oa[1][r] += vv1[r] * p1[r];
}

// oa[m][r] for ONE ih half: sum_j v[e,j] b3[i*33+j] + b3[i*33+32]
__device__ __forceinline__ void init_oa8(float (&oa)[2][4], const float* __restrict__ vj,
                                         const unsigned short* __restrict__ b3f,
                                         const float* __restrict__ b3c,
                                         int B0, int w, int q, int ln, int lane, int ih) {
  s8v b3fr = *(const s8v*)(b3f + (ih * 64 + lane) * 8);
  float cbv = b3c[ih * 16 + ln];
  f32x4 ci = {cbv, cbv, cbv, cbv};
#pragma unroll
  for (int m = 0; m < 2; ++m) {
    int e = B0 + w * 32 + m * 16 + ln;
    const float4 va = *(const float4*)(vj + (size_t)e * 32 + q * 8);
    const float4 vb = *(const float4*)(vj + (size_t)e * 32 + q * 8 + 4);
    s8v t;
    t[0] = (short)f2bf(va.x); t[1] = (short)f2bf(va.y);
    t[2] = (short)f2bf(va.z); t[3] = (short)f2bf(va.w);
    t[4] = (short)f2bf(vb.x); t[5] = (short)f2bf(vb.y);
    t[6] = (short)f2bf(vb.z); t[7] = (short)f2bf(vb.w);
    f32x4 p = __builtin_amdgcn_mfma_f32_16x16x32_bf16(t, b3fr, ci, 0, 0, 0);
#pragma unroll
    for (int r = 0; r < 4; ++r) oa[m][r] = p[r];
  }
}

__device__ __forceinline__ void store_half8(float* __restrict__ out, const float (&oa)[2][4],
                                            int B0, int w, int q, int ln, int ih) {
#pragma unroll
  for (int m = 0; m < 2; ++m)
#pragma unroll
    for (int r = 0; r < 4; ++r) {
      int e = B0 + w * 32 + m * 16 + q * 4 + r;
      out[(size_t)e * 32 + ih * 16 + ln] = oa[m][r];
    }
}

// ---------------- fused main kernel ----------------
// 512 threads (8 waves), 256 edges/block; wave w owns edges [B0+w*32, B0+w*32+32).
__global__ __launch_bounds__(512, 4) void fnn_fused(
    const float* __restrict__ pos_i, const float* __restrict__ pos_j,
    const float* __restrict__ vj, const float* __restrict__ W1,
    const float* __restrict__ b1, const float* __restrict__ b2,
    const unsigned short* __restrict__ W2f, const unsigned short* __restrict__ Wg2,
    const unsigned short* __restrict__ b3f, const float* __restrict__ b3c,
    float* __restrict__ out) {
  __shared__ __attribute__((aligned(16))) char smem[53760];
  float* vt = (float*)smem;                                  // [33][260], G-loop phase
  unsigned short* h1c = (unsigned short*)smem;               // [64][136], prologue
  unsigned short* h2n = (unsigned short*)(smem + 17408);     // [64][136], prologue
  unsigned short* Bb  = (unsigned short*)(smem + 34816);     // [2][4096], G-loop
  char* BbChar = smem + 34816;
  float* w1L = (float*)(smem + 51200);                       // [4][128]
  float* b1L = (float*)(smem + 53248);                       // [128]

  const int tid = threadIdx.x;
  const int w = tid >> 6, lane = tid & 63, q = lane >> 4, ln = lane & 15;
  const int B0 = blockIdx.x * EPB;

  // --- stage W1/b1 into LDS (once; keeps them out of registers) ---
  w1L[tid] = W1[tid];                    // 512 threads == 512 floats
  if (tid < 128) b1L[tid] = b1[tid];
  __syncthreads();

  const int hh0 = (tid & 31) * 4;

  // --- stages 1+2 per quarter (64 edges/phase), 2 barriers/qtr ---
  s8v af[2][4];
  for (int qtr = 0; qtr < 4; ++qtr) {
    // stage 1: 512 threads x (4 edges x 4 cols); W1 slice re-read per half (volatile
    // blocks LICM from re-hoisting it into 20 resident registers)
#pragma unroll
    for (int half = 0; half < 4; ++half) {
      int ee = (tid >> 5) + half * 16;
      int eg = B0 + qtr * 64 + ee;
      float2 pi = *(const float2*)(pos_i + (size_t)eg * 2);
      float2 pj = *(const float2*)(pos_j + (size_t)eg * 2);
      f32x4 w0 = *(volatile const f32x4*)&w1L[0 * 128 + hh0];
      f32x4 w1v = *(volatile const f32x4*)&w1L[1 * 128 + hh0];
      f32x4 w2v = *(volatile const f32x4*)&w1L[2 * 128 + hh0];
      f32x4 w3v = *(volatile const f32x4*)&w1L[3 * 128 + hh0];
      f32x4 bb = *(volatile const f32x4*)&b1L[hh0];
      s4v hv;
#pragma unroll
      for (int u = 0; u < 4; ++u) {
        float o = bb[u] + pi.x * w0[u] + pi.y * w1v[u] + pj.x * w2v[u] + pj.y * w3v[u];
        hv[u] = (short)f2bf(fmaxf(o, 0.f));
      }
      *(s4v*)&h1c[ee * 136 + hh0] = hv;
    }
    __syncthreads();   // h1c ready

    // stage 2: 8 waves x 4 tiles: tt = w*4+s covers all 32 (mt,nt) tiles
#pragma unroll
    for (int s = 0; s < 4; ++s) {
      int tt = w * 4 + s, mt = tt >> 3, nt = tt & 7;
      f32x4 a4 = {0.f, 0.f, 0.f, 0.f};
#pragma unroll
      for (int ks = 0; ks < 4; ++ks) {
        s8v afr = *(const s8v*)&h1c[(mt * 16 + ln) * 136 + ks * 32 + q * 8];
        s8v bfr = *(const s8v*)(W2f + ((ks * 8 + nt) * 64 + lane) * 8);
        a4 = __builtin_amdgcn_mfma_f32_16x16x32_bf16(afr, bfr, a4, 0, 0, 0);
      }
      float b2v = b2[nt * 16 + ln];
      int eb = mt * 16 + q * 4;
      int kc = nt * 16 + ln;
#pragma unroll
      for (int r = 0; r < 4; ++r)
        h2n[(eb + r) * 136 + kc] = f2bf(fmaxf(a4[r] + b2v, 0.f));
    }
    __syncthreads();   // h2n ready

    // extraction: wave w's 32 edges live in qtr w>>1, sub-block (w&1)*32
    if ((w >> 1) == qtr) {
#pragma unroll
      for (int m = 0; m < 2; ++m)
#pragma unroll
        for (int ks = 0; ks < 4; ++ks)
          af[m][ks] = *(const s8v*)&h2n[(((w & 1) * 32 + m * 16 + ln)) * 136 + ks * 32 + q * 8];
    }
  }

  // --- prime chunk 0 into Bb (region disjoint from prologue buffers) ---
  {
    const unsigned short* src = Wg2 + tid * 8;
    char* dstb = BbChar + w * 1024;   // wave-uniform base
    ld16_g2l(src, dstb);
  }
  __syncthreads();   // extraction h2n reads drained before vt overwrite

  // --- oa init for ih=0 (w1r pressure gone; af live) ---
  float oa[2][4];
  init_oa8(oa, vj, b3f, b3c, B0, w, q, ln, lane, 0);

  // --- build vt: vt[j][e] = v[e,j] (f32), row 32 = 1.0 (threads 0..255) ---
  if (tid < 256) {
    const float* vrow = vj + (size_t)(B0 + tid) * 32;
#pragma unroll
    for (int j4 = 0; j4 < 8; ++j4) {
      float4 vv = *(const float4*)(vrow + j4 * 4);
      vt[(j4 * 4 + 0) * 260 + tid] = vv.x;
      vt[(j4 * 4 + 1) * 260 + tid] = vv.y;
      vt[(j4 * 4 + 2) * 260 + tid] = vv.z;
      vt[(j4 * 4 + 3) * 260 + tid] = vv.w;
    }
    vt[32 * 260 + tid] = 1.0f;
  }
  __syncthreads();   // vt ready; barrier drain also covers chunk-0 staging

  const float* vp0 = vt + w * 32 + q * 4;

  // --- G-loop: 33 chunks x 2 tiles, shared-LDS double-buffer, 1 barrier/chunk ---
#pragma unroll 1
  for (int c = 0; c < 16; ++c) {        // tiles 0..31, output half ih=0
    const unsigned short* buf = Bb + (c & 1) * 4096;
    {
      const unsigned short* src = Wg2 + (size_t)(c + 1) * 4096 + tid * 8;
      char* dstb = BbChar + ((c + 1) & 1) * 8192 + w * 1024;
      ld16_g2l(src, dstb);
    }
    tile_compute(buf, 0, vp0, 2 * c,     lane, af, oa);
    tile_compute(buf, 1, vp0, 2 * c + 1, lane, af, oa);
    __syncthreads();
  }
  {                                     // straddle chunk 16: tile 32 (ih0,j=32), tile 33 (ih1,j=0)
    const unsigned short* buf = Bb;     // 16&1 == 0
    {
      const unsigned short* src = Wg2 + (size_t)17 * 4096 + tid * 8;
      char* dstb = BbChar + 8192 + w * 1024;
      ld16_g2l(src, dstb);
    }
    tile_compute(buf, 0, vp0, 32, lane, af, oa);
    store_half8(out, oa, B0, w, q, ln, 0);                 // ih=0 complete
    init_oa8(oa, vj, b3f, b3c, B0, w, q, ln, lane, 1);     // re-init for ih=1
    tile_compute(buf, 1, vp0, 0, lane, af, oa);
    __syncthreads();
  }
#pragma unroll 1
  for (int c = 17; c < 33; ++c) {       // tiles 34..65, output half ih=1; j = 2c-33, 2c-32
    const unsigned short* buf = Bb + (c & 1) * 4096;
    if (c < 32) {
      const unsigned short* src = Wg2 + (size_t)(c + 1) * 4096 + tid * 8;
      char* dstb = BbChar + ((c + 1) & 1) * 8192 + w * 1024;
      ld16_g2l(src, dstb);
    }
    tile_compute(buf, 0, vp0, 2 * c - 33, lane, af, oa);
    tile_compute(buf, 1, vp0, 2 * c - 32, lane, af, oa);
    __syncthreads();
  }
  store_half8(out, oa, B0, w, q, ln, 1);
}

extern "C" void kernel_launch(void* const* d_in, const int* in_sizes, int n_in,
                              void* d_out, int out_size, void* d_ws, size_t ws_size,
                              hipStream_t stream) {
  const float* pos_i = (const float*)d_in[0];
  const float* pos_j = (const float*)d_in[1];
  const float* vj    = (const float*)d_in[2];
  const float* W1    = (const float*)d_in[3];
  const float* b1    = (const float*)d_in[4];
  const float* W2    = (const float*)d_in[5];
  const float* b2    = (const float*)d_in[6];
  const float* W3    = (const float*)d_in[7];
  const float* b3    = (const float*)d_in[8];
  float* outp = (float*)d_out;

  unsigned short* Wg2 = (unsigned short*)d_ws;
  unsigned short* W2f = (unsigned short*)((char*)d_ws + 270336);
  unsigned short* b3f = (unsigned short*)((char*)d_ws + 303104);
  float*          b3c = (float*)((char*)d_ws + 305152);

  prep_pack<<<528, 256, 0, stream>>>(W2, W3, b3, Wg2, W2f, b3f, b3c);
  fnn_fused<<<NBLK, 512, 0, stream>>>(pos_i, pos_j, vj, W1, b1, b2, W2f, Wg2, b3f, b3c, outp);
}